// Round 5
// baseline (153.287 us; speedup 1.0000x reference)
//
#include <hip/hip_runtime.h>
#include <stdint.h>

// B=2,H=16 -> BH=32; S=2048, D=64. chunk_size telescopes out:
// out = causal attention with phi(s)=s+0.5*s^2, s=(q*D^-0.5).k
#define SEQ  2048
#define DH   64
#define BH_N 32
#define SCALE 0.125f

typedef __attribute__((ext_vector_type(8))) short short8;   // 8 bf16
typedef __attribute__((ext_vector_type(4))) short short4b;  // 4 bf16
typedef __attribute__((ext_vector_type(4))) float f32x4;    // MFMA C/D

static __device__ __forceinline__ unsigned short f2bf(float f) {
  unsigned int u = __float_as_uint(f);
  u += 0x7fffu + ((u >> 16) & 1u);   // RNE
  return (unsigned short)(u >> 16);
}
// pack RNE(a)|RNE(b)<<16 with one v_perm for the pack
static __device__ __forceinline__ unsigned packbf(float a, float b) {
  unsigned ua = __float_as_uint(a); ua += 0x7fffu + ((ua >> 16) & 1u);
  unsigned ub = __float_as_uint(b); ub += 0x7fffu + ((ub >> 16) & 1u);
  return __builtin_amdgcn_perm(ub, ua, 0x07060302);  // [ub_hi16 : ua_hi16]
}

typedef __attribute__((address_space(1))) const unsigned char* gp1;
typedef __attribute__((address_space(3))) unsigned char* lp3;
static __device__ __forceinline__ void stage16(const void* g, void* l) {
  __builtin_amdgcn_global_load_lds((gp1)g, (lp3)l, 16, 0, 0);
}

// ---------------------------------------------------------------------------
// Prep: per (bh, 64-key tile) produce stage-ready 16B units (512/tile):
//  kb2 unit u = c*64+key (c=ks*4+quad): shorts j = K[key][ks*32+quad*8+j] (bf16)
//  vt2 unit u = kgp*256+ft*64+quad*16+low: shorts j: kg=kgp*2+(j>>2),
//      key=kg*16+quad*4+(j&3), value = V[key][ft*16+low] (bf16)
// Coalesced float4 reads -> LDS repack -> coalesced uint4 writes.
// ---------------------------------------------------------------------------
__global__ __launch_bounds__(256) void prep_kernel(
    const float* __restrict__ kin, const float* __restrict__ vin,
    unsigned short* __restrict__ kb2, unsigned short* __restrict__ vt2)
{
  const int sb = blockIdx.x;    // 0..31 (64 keys each)
  const int bh = blockIdx.y;    // 0..31
  const int t  = threadIdx.x;   // 0..255
  __shared__ __align__(16) unsigned short lds[4096];
  const size_t base  = ((size_t)bh * SEQ + (size_t)sb * 64) * DH;
  const size_t obase = ((size_t)bh * 32 + sb) * 4096;   // shorts per tile

  // ---- K ----
  #pragma unroll
  for (int i = 0; i < 4; ++i) {
    int idx = i * 256 + t, key = idx >> 4, F = (idx & 15) * 4;
    float4 f = *reinterpret_cast<const float4*>(kin + base + key * DH + F);
    int c = (F >> 5) * 4 + ((F >> 3) & 3), jh = (F >> 2) & 1;
    uint2 pk; pk.x = packbf(f.x, f.y); pk.y = packbf(f.z, f.w);
    *reinterpret_cast<uint2*>(lds + (c * 64 + key) * 8 + jh * 4) = pk;
  }
  __syncthreads();
  #pragma unroll
  for (int uu = 0; uu < 2; ++uu) {
    int u = uu * 256 + t;
    *reinterpret_cast<uint4*>(kb2 + obase + u * 8) =
        *reinterpret_cast<const uint4*>(lds + u * 8);
  }
  __syncthreads();
  // ---- V ----
  #pragma unroll
  for (int i = 0; i < 4; ++i) {
    int idx = i * 256 + t, key = idx >> 4, F = (idx & 15) * 4;
    float4 f = *reinterpret_cast<const float4*>(vin + base + key * DH + F);
    int kgp = key >> 5, qd = (key >> 2) & 3, jj = ((key >> 4) & 1) * 4 + (key & 3);
    int u0 = kgp * 256 + (F >> 4) * 64 + qd * 16 + (F & 15);
    lds[(u0 + 0) * 8 + jj] = f2bf(f.x);
    lds[(u0 + 1) * 8 + jj] = f2bf(f.y);
    lds[(u0 + 2) * 8 + jj] = f2bf(f.z);
    lds[(u0 + 3) * 8 + jj] = f2bf(f.w);
  }
  __syncthreads();
  #pragma unroll
  for (int uu = 0; uu < 2; ++uu) {
    int u = uu * 256 + t;
    *reinterpret_cast<uint4*>(vt2 + obase + u * 8) =
        *reinterpret_cast<const uint4*>(lds + u * 8);
  }
}

// ---------------------------------------------------------------------------
// attn: 1-D grid 512, 256 threads (4 waves), 32KB LDS -> 5 blocks/CU.
// XCD swizzle: bh = (b&7)|((b>>3&3)<<3) so a bh's 16 blocks share one XCD's
// L2; qa = b>>5 (longest blocks first). Block owns q-tiles B=31-qa, A=qa.
// Waves 0,1 = tile B row-halves (active every iter); waves 2,3 = tile A
// (active t<=qa). One kv-tile staged per iter (K 8KB + V 8KB), wave w DMAs
// quarter w; double-buffered, prefetch in flight across raw s_barrier
// (vmcnt(4)). Each wave owns complete output rows -> no split-K merge.
// S^T = K.Q^T (16x16x32) -> phi in-register -> P^T B-frags ->
// O^T += V^T.P^T (16x16x16) -> dwordx4 stores.
// ---------------------------------------------------------------------------
__global__ __launch_bounds__(256, 5) void attn_kernel(
    const float* __restrict__ q,
    const unsigned short* __restrict__ kb2,
    const unsigned short* __restrict__ vt2,
    float* __restrict__ out)
{
  const int b0   = blockIdx.x;        // 0..511
  const int bh   = (b0 & 7) | (((b0 >> 3) & 3) << 3);
  const int qa   = b0 >> 5;           // 0..15
  const int tid  = threadIdx.x;
  const int w    = tid >> 6;          // 0..3
  const int lane = tid & 63;
  const int low  = lane & 15;
  const int quad = lane >> 4;
  const int rh   = w & 1;             // q-row half within wave's tile

  const int mytile = (w < 2) ? (31 - qa) : qa;   // waves 0,1 -> B; 2,3 -> A
  const int nIter  = 32 - qa;                    // kv tiles 0..31-qa
  const int r0     = mytile * 64 + rh * 32;

  // [buf][8192 shorts]: K units in [0,4096), V units in [4096,8192)
  __shared__ __align__(16) unsigned short buf[2][8192];

  const unsigned short* kb_h = kb2 + (size_t)bh * 32 * 4096;
  const unsigned short* v2_h = vt2 + (size_t)bh * 32 * 4096;

  // Q B-frags (scaled bf16), registers for whole kernel
  short8 aq[2][2];
  #pragma unroll
  for (int h = 0; h < 2; ++h) {
    const float* qp =
        q + ((size_t)bh * SEQ + r0 + h * 16 + low) * DH + quad * 8;
    #pragma unroll
    for (int ks = 0; ks < 2; ++ks) {
      float4 f0 = *reinterpret_cast<const float4*>(qp + ks * 32);
      float4 f1 = *reinterpret_cast<const float4*>(qp + ks * 32 + 4);
      uint4 uv;
      uv.x = packbf(f0.x * SCALE, f0.y * SCALE);
      uv.y = packbf(f0.z * SCALE, f0.w * SCALE);
      uv.z = packbf(f1.x * SCALE, f1.y * SCALE);
      uv.w = packbf(f1.z * SCALE, f1.w * SCALE);
      aq[h][ks] = __builtin_bit_cast(short8, uv);
    }
  }

  f32x4 oacc[2][4];   // O^T: lane holds O[q=r0+h*16+low][f=ft*16+quad*4+r]
  #pragma unroll
  for (int h = 0; h < 2; ++h)
    #pragma unroll
    for (int i = 0; i < 4; ++i) oacc[h][i] = (f32x4){0.f, 0.f, 0.f, 0.f};

  // staging role: wave w covers shorts [w*2048, w*2048+2048) of the buffer;
  // source = K tile half (w<2) or V tile half (w>=2), contiguous 1KB streams.
  const unsigned short* gsrc = (w < 2) ? kb_h : v2_h;
  const int ghalf = (w & 1) * 2048;

  #define STAGE(T, B)                                                          \
    do {                                                                       \
      const unsigned short* gs_ = gsrc + (size_t)(T) * 4096 + ghalf;           \
      unsigned short* ld_ = &buf[B][w * 2048];                                 \
      _Pragma("unroll")                                                        \
      for (int r_ = 0; r_ < 4; ++r_)                                           \
        stage16(gs_ + r_ * 512 + lane * 8, ld_ + r_ * 512 + lane * 8);         \
    } while (0)

  STAGE(0, 0);

  for (int t = 0; t < nIter; ++t) {
    const int bb = t & 1;
    __builtin_amdgcn_s_barrier();                       // buf bb^1 free
    if (t < nIter - 1) {
      STAGE(t + 1, bb ^ 1);                             // prefetch in flight
      asm volatile("s_waitcnt vmcnt(4)" ::: "memory");  // tile-t loads landed
    } else {
      asm volatile("s_waitcnt vmcnt(0)" ::: "memory");
    }
    __builtin_amdgcn_s_barrier();                       // everyone's landed
    asm volatile("" ::: "memory");

    if (t > mytile) continue;                           // wave-uniform
    const bool diag = (t == mytile);
    const unsigned short* kT = &buf[bb][0];
    const unsigned short* vT = &buf[bb][4096];

    #pragma unroll
    for (int ntp = 0; ntp < 2; ++ntp) {
      short8 vf[4];
      #pragma unroll
      for (int ft = 0; ft < 4; ++ft)
        vf[ft] = *reinterpret_cast<const short8*>(
            vT + ((ntp * 4 + ft) * 64 + quad * 16 + low) * 8);

      #pragma unroll
      for (int sub = 0; sub < 2; ++sub) {
        const int nt = ntp * 2 + sub;
        f32x4 s0 = (f32x4){0.f, 0.f, 0.f, 0.f};
        f32x4 s1 = (f32x4){0.f, 0.f, 0.f, 0.f};
        #pragma unroll
        for (int ks = 0; ks < 2; ++ks) {
          short8 kf = *reinterpret_cast<const short8*>(
              kT + ((ks * 4 + quad) * 64 + nt * 16 + low) * 8);
          s0 = __builtin_amdgcn_mfma_f32_16x16x32_bf16(kf, aq[0][ks], s0, 0, 0, 0);
          s1 = __builtin_amdgcn_mfma_f32_16x16x32_bf16(kf, aq[1][ks], s1, 0, 0, 0);
        }
        #pragma unroll
        for (int h = 0; h < 2; ++h) {
          f32x4 sv = h ? s1 : s0;
          float pv[4];
          #pragma unroll
          for (int r = 0; r < 4; ++r) {
            float x = sv[r];
            pv[r] = __builtin_fmaf(0.5f * x, x, x);     // s + 0.5 s^2
          }
          if (diag) {
            #pragma unroll
            for (int r = 0; r < 4; ++r)
              if ((nt * 16 + quad * 4 + r) > (rh * 32 + h * 16 + low)) pv[r] = 0.f;
          }
          uint2 du; du.x = packbf(pv[0], pv[1]); du.y = packbf(pv[2], pv[3]);
          short4b pf = __builtin_bit_cast(short4b, du);  // P^T B-frag
          #pragma unroll
          for (int ft = 0; ft < 4; ++ft) {
            short4b va = sub
                ? __builtin_shufflevector(vf[ft], vf[ft], 4, 5, 6, 7)
                : __builtin_shufflevector(vf[ft], vf[ft], 0, 1, 2, 3);
            oacc[h][ft] = __builtin_amdgcn_mfma_f32_16x16x16bf16_1k(
                va, pf, oacc[h][ft], 0, 0, 0);
          }
        }
      }
    }
  }

  // ---- epilogue: each wave owns complete rows, direct dwordx4 stores ----
  #pragma unroll
  for (int h = 0; h < 2; ++h)
    #pragma unroll
    for (int ft = 0; ft < 4; ++ft)
      *reinterpret_cast<f32x4*>(
          out + ((size_t)bh * SEQ + r0 + h * 16 + low) * DH + ft * 16 + quad * 4) =
          oacc[h][ft];
}

extern "C" void kernel_launch(void* const* d_in, const int* in_sizes, int n_in,
                              void* d_out, int out_size, void* d_ws, size_t ws_size,
                              hipStream_t stream)
{
  const float* q = (const float*)d_in[0];
  const float* k = (const float*)d_in[1];
  const float* v = (const float*)d_in[2];
  float* out = (float*)d_out;

  unsigned short* kb2 = (unsigned short*)d_ws;             // 8.4 MB bf16 packed
  unsigned short* vt2 = kb2 + (size_t)BH_N * SEQ * DH;     // 8.4 MB bf16 packed

  prep_kernel<<<dim3(32, BH_N), 256, 0, stream>>>(k, v, kb2, vt2);
  attn_kernel<<<512, 256, 0, stream>>>(q, kb2, vt2, out);
}

// Round 6
// 129.585 us; speedup vs baseline: 1.1829x; 1.1829x over previous
//
#include <hip/hip_runtime.h>
#include <stdint.h>

// B=2,H=16 -> BH=32; S=2048, D=64. chunk_size telescopes out:
// out = causal attention with phi(s)=s+0.5*s^2, s=(q*D^-0.5).k
#define SEQ  2048
#define DH   64
#define BH_N 32
#define SCALE 0.125f

typedef __attribute__((ext_vector_type(8))) short short8;   // 8 bf16
typedef __attribute__((ext_vector_type(4))) short short4b;  // 4 bf16
typedef __attribute__((ext_vector_type(4))) float f32x4;    // MFMA C/D

static __device__ __forceinline__ unsigned short f2bf(float f) {
  unsigned int u = __float_as_uint(f);
  u += 0x7fffu + ((u >> 16) & 1u);   // RNE
  return (unsigned short)(u >> 16);
}
// pack RNE(a)|RNE(b)<<16 with one v_perm for the pack
static __device__ __forceinline__ unsigned packbf(float a, float b) {
  unsigned ua = __float_as_uint(a); ua += 0x7fffu + ((ua >> 16) & 1u);
  unsigned ub = __float_as_uint(b); ub += 0x7fffu + ((ub >> 16) & 1u);
  return __builtin_amdgcn_perm(ub, ua, 0x07060302);  // [ub_hi16 : ua_hi16]
}

typedef __attribute__((address_space(1))) const unsigned char* gp1;
typedef __attribute__((address_space(3))) unsigned char* lp3;
static __device__ __forceinline__ void stage16(const void* g, void* l) {
  __builtin_amdgcn_global_load_lds((gp1)g, (lp3)l, 16, 0, 0);
}

// ---------------------------------------------------------------------------
// Prep: per (bh, 64-key tile) produce stage-ready 16B units (512/tile):
//  kb2 unit u = c*64+key (c=ks*4+quad): shorts j = K[key][ks*32+quad*8+j] (bf16)
//  vt2 unit u = kgp*256+ft*64+quad*16+low: shorts j: kg=kgp*2+(j>>2),
//      key=kg*16+quad*4+(j&3), value = V[key][ft*16+low] (bf16)
// Coalesced float4 reads -> LDS repack -> coalesced uint4 writes.
// ---------------------------------------------------------------------------
__global__ __launch_bounds__(256) void prep_kernel(
    const float* __restrict__ kin, const float* __restrict__ vin,
    unsigned short* __restrict__ kb2, unsigned short* __restrict__ vt2)
{
  const int sb = blockIdx.x;    // 0..31 (64 keys each)
  const int bh = blockIdx.y;    // 0..31
  const int t  = threadIdx.x;   // 0..255
  __shared__ __align__(16) unsigned short lds[4096];
  const size_t base  = ((size_t)bh * SEQ + (size_t)sb * 64) * DH;
  const size_t obase = ((size_t)bh * 32 + sb) * 4096;   // shorts per tile

  // ---- K ----
  #pragma unroll
  for (int i = 0; i < 4; ++i) {
    int idx = i * 256 + t, key = idx >> 4, F = (idx & 15) * 4;
    float4 f = *reinterpret_cast<const float4*>(kin + base + key * DH + F);
    int c = (F >> 5) * 4 + ((F >> 3) & 3), jh = (F >> 2) & 1;
    uint2 pk; pk.x = packbf(f.x, f.y); pk.y = packbf(f.z, f.w);
    *reinterpret_cast<uint2*>(lds + (c * 64 + key) * 8 + jh * 4) = pk;
  }
  __syncthreads();
  #pragma unroll
  for (int uu = 0; uu < 2; ++uu) {
    int u = uu * 256 + t;
    *reinterpret_cast<uint4*>(kb2 + obase + u * 8) =
        *reinterpret_cast<const uint4*>(lds + u * 8);
  }
  __syncthreads();
  // ---- V ----
  #pragma unroll
  for (int i = 0; i < 4; ++i) {
    int idx = i * 256 + t, key = idx >> 4, F = (idx & 15) * 4;
    float4 f = *reinterpret_cast<const float4*>(vin + base + key * DH + F);
    int kgp = key >> 5, qd = (key >> 2) & 3, jj = ((key >> 4) & 1) * 4 + (key & 3);
    int u0 = kgp * 256 + (F >> 4) * 64 + qd * 16 + (F & 15);
    lds[(u0 + 0) * 8 + jj] = f2bf(f.x);
    lds[(u0 + 1) * 8 + jj] = f2bf(f.y);
    lds[(u0 + 2) * 8 + jj] = f2bf(f.z);
    lds[(u0 + 3) * 8 + jj] = f2bf(f.w);
  }
  __syncthreads();
  #pragma unroll
  for (int uu = 0; uu < 2; ++uu) {
    int u = uu * 256 + t;
    *reinterpret_cast<uint4*>(vt2 + obase + u * 8) =
        *reinterpret_cast<const uint4*>(lds + u * 8);
  }
}

// ---------------------------------------------------------------------------
// attn: 1-D grid 1024 (= 32 bh x 32 q-tiles), 128 threads (2 waves), 32KB LDS
// -> 5 blocks/CU (LDS-capped), 10 waves/CU, EVERY wave active EVERY iteration.
// Mapping: qt = 31 - (b0>>5)  (longest blocks dispatch first);
//          bh = b0 & 31       (bh's blocks -> same XCD mod 8, L2 affinity).
// Wave w handles q-rows qt*64 + w*32 .. +32 (two 16-row MFMA halves sharing
// each V fragment). One kv-tile staged per iter: wave 0 DMAs K (8x1KB),
// wave 1 DMAs V; double-buffered, prefetch in flight across raw s_barrier
// (vmcnt(8)). Loop runs exactly kv=0..qt (no idle branch).
// S^T = K.Q^T (16x16x32) -> phi in-register -> P^T B-frags ->
// O^T += V^T.P^T (16x16x16) -> dwordx4 stores.
// ---------------------------------------------------------------------------
__global__ __launch_bounds__(128, 2) void attn_kernel(
    const float* __restrict__ q,
    const unsigned short* __restrict__ kb2,
    const unsigned short* __restrict__ vt2,
    float* __restrict__ out)
{
  const int b0   = blockIdx.x;        // 0..1023
  const int bh   = b0 & 31;
  const int qt   = 31 - (b0 >> 5);    // 0..31, big blocks first
  const int tid  = threadIdx.x;
  const int w    = tid >> 6;          // 0..1
  const int lane = tid & 63;
  const int low  = lane & 15;
  const int quad = lane >> 4;
  const int rh   = w;                 // q-row half within the tile

  const int nIter = qt + 1;           // kv tiles 0..qt
  const int r0    = qt * 64 + rh * 32;

  // [buf][8192 shorts]: K units in [0,4096), V units in [4096,8192)
  __shared__ __align__(16) unsigned short buf[2][8192];

  const unsigned short* kb_h = kb2 + (size_t)bh * 32 * 4096;
  const unsigned short* v2_h = vt2 + (size_t)bh * 32 * 4096;

  // Q B-frags (scaled bf16), registers for whole kernel
  short8 aq[2][2];
  #pragma unroll
  for (int h = 0; h < 2; ++h) {
    const float* qp =
        q + ((size_t)bh * SEQ + r0 + h * 16 + low) * DH + quad * 8;
    #pragma unroll
    for (int ks = 0; ks < 2; ++ks) {
      float4 f0 = *reinterpret_cast<const float4*>(qp + ks * 32);
      float4 f1 = *reinterpret_cast<const float4*>(qp + ks * 32 + 4);
      uint4 uv;
      uv.x = packbf(f0.x * SCALE, f0.y * SCALE);
      uv.y = packbf(f0.z * SCALE, f0.w * SCALE);
      uv.z = packbf(f1.x * SCALE, f1.y * SCALE);
      uv.w = packbf(f1.z * SCALE, f1.w * SCALE);
      aq[h][ks] = __builtin_bit_cast(short8, uv);
    }
  }

  f32x4 oacc[2][4];   // O^T: lane holds O[q=r0+h*16+low][f=ft*16+quad*4+r]
  #pragma unroll
  for (int h = 0; h < 2; ++h)
    #pragma unroll
    for (int i = 0; i < 4; ++i) oacc[h][i] = (f32x4){0.f, 0.f, 0.f, 0.f};

  // staging role: wave 0 -> K tile half of buf, wave 1 -> V tile half.
  const unsigned short* gsrc = w ? v2_h : kb_h;

  #define STAGE(T, B)                                                          \
    do {                                                                       \
      const unsigned short* gs_ = gsrc + (size_t)(T) * 4096;                   \
      unsigned short* ld_ = &buf[B][w * 4096];                                 \
      _Pragma("unroll")                                                        \
      for (int r_ = 0; r_ < 8; ++r_)                                           \
        stage16(gs_ + r_ * 512 + lane * 8, ld_ + r_ * 512 + lane * 8);         \
    } while (0)

  STAGE(0, 0);

  for (int t = 0; t < nIter; ++t) {
    const int bb = t & 1;
    __builtin_amdgcn_s_barrier();                       // buf bb^1 free
    if (t < nIter - 1) {
      STAGE(t + 1, bb ^ 1);                             // prefetch in flight
      asm volatile("s_waitcnt vmcnt(8)" ::: "memory");  // tile-t loads landed
    } else {
      asm volatile("s_waitcnt vmcnt(0)" ::: "memory");
    }
    __builtin_amdgcn_s_barrier();                       // everyone's landed
    asm volatile("" ::: "memory");

    const bool diag = (t == qt);
    const unsigned short* kT = &buf[bb][0];
    const unsigned short* vT = &buf[bb][4096];

    #pragma unroll
    for (int ntp = 0; ntp < 2; ++ntp) {
      short8 vf[4];
      #pragma unroll
      for (int ft = 0; ft < 4; ++ft)
        vf[ft] = *reinterpret_cast<const short8*>(
            vT + ((ntp * 4 + ft) * 64 + quad * 16 + low) * 8);

      #pragma unroll
      for (int sub = 0; sub < 2; ++sub) {
        const int nt = ntp * 2 + sub;
        f32x4 s0 = (f32x4){0.f, 0.f, 0.f, 0.f};
        f32x4 s1 = (f32x4){0.f, 0.f, 0.f, 0.f};
        #pragma unroll
        for (int ks = 0; ks < 2; ++ks) {
          short8 kf = *reinterpret_cast<const short8*>(
              kT + ((ks * 4 + quad) * 64 + nt * 16 + low) * 8);
          s0 = __builtin_amdgcn_mfma_f32_16x16x32_bf16(kf, aq[0][ks], s0, 0, 0, 0);
          s1 = __builtin_amdgcn_mfma_f32_16x16x32_bf16(kf, aq[1][ks], s1, 0, 0, 0);
        }
        #pragma unroll
        for (int h = 0; h < 2; ++h) {
          f32x4 sv = h ? s1 : s0;
          float pv[4];
          #pragma unroll
          for (int r = 0; r < 4; ++r) {
            float x = sv[r];
            pv[r] = __builtin_fmaf(0.5f * x, x, x);     // s + 0.5 s^2
          }
          if (diag) {
            #pragma unroll
            for (int r = 0; r < 4; ++r)
              if ((nt * 16 + quad * 4 + r) > (rh * 32 + h * 16 + low)) pv[r] = 0.f;
          }
          uint2 du; du.x = packbf(pv[0], pv[1]); du.y = packbf(pv[2], pv[3]);
          short4b pf = __builtin_bit_cast(short4b, du);  // P^T B-frag
          #pragma unroll
          for (int ft = 0; ft < 4; ++ft) {
            short4b va = sub
                ? __builtin_shufflevector(vf[ft], vf[ft], 4, 5, 6, 7)
                : __builtin_shufflevector(vf[ft], vf[ft], 0, 1, 2, 3);
            oacc[h][ft] = __builtin_amdgcn_mfma_f32_16x16x16bf16_1k(
                va, pf, oacc[h][ft], 0, 0, 0);
          }
        }
      }
    }
  }

  // ---- epilogue: each wave owns complete rows, direct dwordx4 stores ----
  #pragma unroll
  for (int h = 0; h < 2; ++h)
    #pragma unroll
    for (int ft = 0; ft < 4; ++ft)
      *reinterpret_cast<f32x4*>(
          out + ((size_t)bh * SEQ + r0 + h * 16 + low) * DH + ft * 16 + quad * 4) =
          oacc[h][ft];
}

extern "C" void kernel_launch(void* const* d_in, const int* in_sizes, int n_in,
                              void* d_out, int out_size, void* d_ws, size_t ws_size,
                              hipStream_t stream)
{
  const float* q = (const float*)d_in[0];
  const float* k = (const float*)d_in[1];
  const float* v = (const float*)d_in[2];
  float* out = (float*)d_out;

  unsigned short* kb2 = (unsigned short*)d_ws;             // 8.4 MB bf16 packed
  unsigned short* vt2 = kb2 + (size_t)BH_N * SEQ * DH;     // 8.4 MB bf16 packed

  prep_kernel<<<dim3(32, BH_N), 256, 0, stream>>>(k, v, kb2, vt2);
  attn_kernel<<<1024, 128, 0, stream>>>(q, kb2, vt2, out);
}

// Round 7
// 129.470 us; speedup vs baseline: 1.1840x; 1.0009x over previous
//
#include <hip/hip_runtime.h>
#include <stdint.h>

// B=2,H=16 -> BH=32; S=2048, D=64. chunk_size telescopes out:
// out = causal attention with phi(s)=s+0.5*s^2, s=(q*D^-0.5).k
#define SEQ  2048
#define DH   64
#define BH_N 32
#define SCALE 0.125f

typedef __attribute__((ext_vector_type(8))) short short8;   // 8 bf16
typedef __attribute__((ext_vector_type(4))) short short4b;  // 4 bf16
typedef __attribute__((ext_vector_type(4))) float f32x4;    // MFMA C/D

static __device__ __forceinline__ unsigned short f2bf(float f) {
  unsigned int u = __float_as_uint(f);
  u += 0x7fffu + ((u >> 16) & 1u);   // RNE
  return (unsigned short)(u >> 16);
}
#if __has_builtin(__builtin_amdgcn_cvt_pk_bf16_f32)
typedef __attribute__((ext_vector_type(2))) __bf16 bf16x2;
static __device__ __forceinline__ unsigned packbf(float a, float b) {
  return __builtin_bit_cast(unsigned, __builtin_amdgcn_cvt_pk_bf16_f32(a, b));
}
#else
static __device__ __forceinline__ unsigned packbf(float a, float b) {
  unsigned ua = __float_as_uint(a); ua += 0x7fffu + ((ua >> 16) & 1u);
  unsigned ub = __float_as_uint(b); ub += 0x7fffu + ((ub >> 16) & 1u);
  return __builtin_amdgcn_perm(ub, ua, 0x07060302);  // [b_hi16 : a_hi16]
}
#endif

// ---------------------------------------------------------------------------
// Prep: per (bh, 64-key tile) produce stage-ready 16B units (512/tile):
//  kb2 unit u = c*64+key (c=ks*4+quad): shorts j = K[key][ks*32+quad*8+j] (bf16)
//  vt2 unit u = kgp*256+ft*64+quad*16+low: shorts j: kg=kgp*2+(j>>2),
//      key=kg*16+quad*4+(j&3), value = V[key][ft*16+low] (bf16)
// ---------------------------------------------------------------------------
__global__ __launch_bounds__(256) void prep_kernel(
    const float* __restrict__ kin, const float* __restrict__ vin,
    unsigned short* __restrict__ kb2, unsigned short* __restrict__ vt2)
{
  const int sb = blockIdx.x;    // 0..31 (64 keys each)
  const int bh = blockIdx.y;    // 0..31
  const int t  = threadIdx.x;   // 0..255
  __shared__ __align__(16) unsigned short lds[4096];
  const size_t base  = ((size_t)bh * SEQ + (size_t)sb * 64) * DH;
  const size_t obase = ((size_t)bh * 32 + sb) * 4096;   // shorts per tile

  // ---- K ----
  #pragma unroll
  for (int i = 0; i < 4; ++i) {
    int idx = i * 256 + t, key = idx >> 4, F = (idx & 15) * 4;
    float4 f = *reinterpret_cast<const float4*>(kin + base + key * DH + F);
    int c = (F >> 5) * 4 + ((F >> 3) & 3), jh = (F >> 2) & 1;
    uint2 pk; pk.x = packbf(f.x, f.y); pk.y = packbf(f.z, f.w);
    *reinterpret_cast<uint2*>(lds + (c * 64 + key) * 8 + jh * 4) = pk;
  }
  __syncthreads();
  #pragma unroll
  for (int uu = 0; uu < 2; ++uu) {
    int u = uu * 256 + t;
    *reinterpret_cast<uint4*>(kb2 + obase + u * 8) =
        *reinterpret_cast<const uint4*>(lds + u * 8);
  }
  __syncthreads();
  // ---- V ----
  #pragma unroll
  for (int i = 0; i < 4; ++i) {
    int idx = i * 256 + t, key = idx >> 4, F = (idx & 15) * 4;
    float4 f = *reinterpret_cast<const float4*>(vin + base + key * DH + F);
    int kgp = key >> 5, qd = (key >> 2) & 3, jj = ((key >> 4) & 1) * 4 + (key & 3);
    int u0 = kgp * 256 + (F >> 4) * 64 + qd * 16 + (F & 15);
    lds[(u0 + 0) * 8 + jj] = f2bf(f.x);
    lds[(u0 + 1) * 8 + jj] = f2bf(f.y);
    lds[(u0 + 2) * 8 + jj] = f2bf(f.z);
    lds[(u0 + 3) * 8 + jj] = f2bf(f.w);
  }
  __syncthreads();
  #pragma unroll
  for (int uu = 0; uu < 2; ++uu) {
    int u = uu * 256 + t;
    *reinterpret_cast<uint4*>(vt2 + obase + u * 8) =
        *reinterpret_cast<const uint4*>(lds + u * 8);
  }
}

// ---------------------------------------------------------------------------
// attn: grid 512 (= 32 bh x 16 tile-pairs), 256 threads (4 waves), 32KB LDS.
// bh = b0&31 (bh's 16 blocks -> one XCD: L2 affinity). g = b0>>5 (0..15),
// j = g<8 ? g : 23-g  ->  per-CU coset {c, c+256} sums to exactly 34 steps.
// Block owns adjacent q-tiles A=2j, B=2j+1; ONE staged kv stream tau=0..2j+1
// feeds all 128 q-rows (halves staged bytes per compute vs one-tile blocks).
// Wave w: tile = (w<2)? B : A, row-half rh=w&1 (32 rows). A-waves idle only
// at the single last step.
// Staging via VGPR (vector global_load_dwordx4 -> ds_write_b128), NOT
// global_load_lds: loads for tau+1 issue at iter top (latency hidden under
// compute), writes land in buf^1 at iter end, ONE raw s_barrier per tile
// (safety: my writes of tile tau drained by lgkmcnt(0) before MY barrier;
// all other waves' reads of buf^1 happened before THEIR barrier; my write
// to buf^1 is after MY barrier which is after ALL arrivals).
// S^T = K.Q^T (16x16x32) -> phi in-register -> P^T B-frags ->
// O^T += V^T.P^T (16x16x16) -> dwordx4 stores.
// ---------------------------------------------------------------------------
__global__ __launch_bounds__(256, 2) void attn_kernel(
    const float* __restrict__ q,
    const unsigned short* __restrict__ kb2,
    const unsigned short* __restrict__ vt2,
    float* __restrict__ out)
{
  const int b0   = blockIdx.x;        // 0..511
  const int bh   = b0 & 31;
  const int g    = b0 >> 5;           // 0..15
  const int j    = (g < 8) ? g : 23 - g;
  const int last = 2 * j + 1;         // steps tau = 0..last
  const int tid  = threadIdx.x;
  const int w    = tid >> 6;          // 0..3
  const int lane = tid & 63;
  const int low  = lane & 15;
  const int quad = lane >> 4;
  const int rh   = w & 1;

  const int mytile = (w < 2) ? (2 * j + 1) : (2 * j);
  const int r0     = mytile * 64 + rh * 32;

  // [buf][8192 shorts]: K units in [0,4096), V units in [4096,8192)
  __shared__ __align__(16) unsigned short buf[2][8192];

  const unsigned short* kb_h = kb2 + (size_t)bh * 32 * 4096;
  const unsigned short* v2_h = vt2 + (size_t)bh * 32 * 4096;

  // Q B-frags (scaled bf16), registers for whole kernel
  short8 aq[2][2];
  #pragma unroll
  for (int h = 0; h < 2; ++h) {
    const float* qp =
        q + ((size_t)bh * SEQ + r0 + h * 16 + low) * DH + quad * 8;
    #pragma unroll
    for (int ks = 0; ks < 2; ++ks) {
      float4 f0 = *reinterpret_cast<const float4*>(qp + ks * 32);
      float4 f1 = *reinterpret_cast<const float4*>(qp + ks * 32 + 4);
      uint4 uv;
      uv.x = packbf(f0.x * SCALE, f0.y * SCALE);
      uv.y = packbf(f0.z * SCALE, f0.w * SCALE);
      uv.z = packbf(f1.x * SCALE, f1.y * SCALE);
      uv.w = packbf(f1.z * SCALE, f1.w * SCALE);
      aq[h][ks] = __builtin_bit_cast(short8, uv);
    }
  }

  f32x4 oacc[2][4];   // O^T: lane holds O[q=r0+h*16+low][f=ft*16+quad*4+r]
  #pragma unroll
  for (int h = 0; h < 2; ++h)
    #pragma unroll
    for (int i = 0; i < 4; ++i) oacc[h][i] = (f32x4){0.f, 0.f, 0.f, 0.f};

  // staging role: wave w stages 4KB: w 0,1 -> K-tile halves; 2,3 -> V-tile.
  const unsigned short* gsrc = (w < 2) ? kb_h : v2_h;
  const int ghalf  = (w & 1) * 2048;                 // shorts
  const int ldsoff = (w >> 1) * 4096 + ghalf;        // shorts
  uint4 g0, g1, g2, g3;

  #define GLOAD(T)                                                             \
    do {                                                                       \
      const unsigned short* gs_ = gsrc + (size_t)(T) * 4096 + ghalf;           \
      g0 = *reinterpret_cast<const uint4*>(gs_ + 0 * 512 + lane * 8);          \
      g1 = *reinterpret_cast<const uint4*>(gs_ + 1 * 512 + lane * 8);          \
      g2 = *reinterpret_cast<const uint4*>(gs_ + 2 * 512 + lane * 8);          \
      g3 = *reinterpret_cast<const uint4*>(gs_ + 3 * 512 + lane * 8);          \
    } while (0)

  #define DSWRITE(B)                                                           \
    do {                                                                       \
      unsigned short* ld_ = &buf[B][ldsoff] + lane * 8;                        \
      *reinterpret_cast<uint4*>(ld_ + 0 * 512) = g0;                           \
      *reinterpret_cast<uint4*>(ld_ + 1 * 512) = g1;                           \
      *reinterpret_cast<uint4*>(ld_ + 2 * 512) = g2;                           \
      *reinterpret_cast<uint4*>(ld_ + 3 * 512) = g3;                           \
    } while (0)

  // prologue: tile 0 -> buf0
  GLOAD(0);
  DSWRITE(0);

  for (int t = 0; t <= last; ++t) {
    const int bb = t & 1;
    if (t < last) GLOAD(t + 1);                       // issue early, lands
                                                      // under compute
    asm volatile("s_waitcnt lgkmcnt(0)" ::: "memory"); // my tile-t ds_writes
    __builtin_amdgcn_s_barrier();                      // tile t fully in LDS;
                                                       // buf[bb^1] consumed
    asm volatile("" ::: "memory");

    if (t <= mytile) {
      const bool diag = (t == mytile);
      const unsigned short* kT = &buf[bb][0];
      const unsigned short* vT = &buf[bb][4096];

      #pragma unroll
      for (int ntp = 0; ntp < 2; ++ntp) {
        short8 vf[4];
        #pragma unroll
        for (int ft = 0; ft < 4; ++ft)
          vf[ft] = *reinterpret_cast<const short8*>(
              vT + ((ntp * 4 + ft) * 64 + quad * 16 + low) * 8);

        #pragma unroll
        for (int sub = 0; sub < 2; ++sub) {
          const int nt = ntp * 2 + sub;
          f32x4 s0 = (f32x4){0.f, 0.f, 0.f, 0.f};
          f32x4 s1 = (f32x4){0.f, 0.f, 0.f, 0.f};
          #pragma unroll
          for (int ks = 0; ks < 2; ++ks) {
            short8 kf = *reinterpret_cast<const short8*>(
                kT + ((ks * 4 + quad) * 64 + nt * 16 + low) * 8);
            s0 = __builtin_amdgcn_mfma_f32_16x16x32_bf16(kf, aq[0][ks], s0, 0, 0, 0);
            s1 = __builtin_amdgcn_mfma_f32_16x16x32_bf16(kf, aq[1][ks], s1, 0, 0, 0);
          }
          #pragma unroll
          for (int h = 0; h < 2; ++h) {
            f32x4 sv = h ? s1 : s0;
            float pv[4];
            #pragma unroll
            for (int r = 0; r < 4; ++r) {
              float x = sv[r];
              pv[r] = __builtin_fmaf(0.5f * x, x, x);   // s + 0.5 s^2
            }
            if (diag) {
              #pragma unroll
              for (int r = 0; r < 4; ++r)
                if ((nt * 16 + quad * 4 + r) > (rh * 32 + h * 16 + low)) pv[r] = 0.f;
            }
            uint2 du; du.x = packbf(pv[0], pv[1]); du.y = packbf(pv[2], pv[3]);
            short4b pf = __builtin_bit_cast(short4b, du);  // P^T B-frag
            #pragma unroll
            for (int ft = 0; ft < 4; ++ft) {
              short4b va = sub
                  ? __builtin_shufflevector(vf[ft], vf[ft], 4, 5, 6, 7)
                  : __builtin_shufflevector(vf[ft], vf[ft], 0, 1, 2, 3);
              oacc[h][ft] = __builtin_amdgcn_mfma_f32_16x16x16bf16_1k(
                  va, pf, oacc[h][ft], 0, 0, 0);
            }
          }
        }
      }
    }

    if (t < last) DSWRITE(bb ^ 1);   // tile t+1 -> other buffer (data-dep
                                     // waits the global loads; reads of
                                     // buf[bb^1] are all pre-barrier)
  }

  // ---- epilogue: each wave owns complete rows, direct dwordx4 stores ----
  #pragma unroll
  for (int h = 0; h < 2; ++h)
    #pragma unroll
    for (int ft = 0; ft < 4; ++ft)
      *reinterpret_cast<f32x4*>(
          out + ((size_t)bh * SEQ + r0 + h * 16 + low) * DH + ft * 16 + quad * 4) =
          oacc[h][ft];
}

extern "C" void kernel_launch(void* const* d_in, const int* in_sizes, int n_in,
                              void* d_out, int out_size, void* d_ws, size_t ws_size,
                              hipStream_t stream)
{
  const float* q = (const float*)d_in[0];
  const float* k = (const float*)d_in[1];
  const float* v = (const float*)d_in[2];
  float* out = (float*)d_out;

  unsigned short* kb2 = (unsigned short*)d_ws;             // 8.4 MB bf16 packed
  unsigned short* vt2 = kb2 + (size_t)BH_N * SEQ * DH;     // 8.4 MB bf16 packed

  prep_kernel<<<dim3(32, BH_N), 256, 0, stream>>>(k, v, kb2, vt2);
  attn_kernel<<<512, 256, 0, stream>>>(q, kb2, vt2, out);
}